// Round 1
// baseline (833.108 us; speedup 1.0000x reference)
//
#include <hip/hip_runtime.h>

#define FDIM 64

// ---------------- degree histogram ----------------
__global__ __launch_bounds__(256) void k_deg(const int* __restrict__ dst,
                                             int* __restrict__ deg, int E, int N) {
    int i = blockIdx.x * 256 + threadIdx.x;
    int stride = gridDim.x * 256;
    for (; i < E; i += stride) {
        int d = dst[i];
        if ((unsigned)d < (unsigned)N) atomicAdd(&deg[d], 1);
    }
}

// deg(int, in place) -> dinv(float) = rsqrt(deg + 1)   (+1 = self loop)
__global__ __launch_bounds__(256) void k_dinv(float* __restrict__ buf, int N) {
    int i = blockIdx.x * 256 + threadIdx.x;
    if (i < N) {
        int dg = reinterpret_cast<const int*>(buf)[i] + 1;
        buf[i] = rsqrtf((float)dg);
    }
}

// ---------------- dense GEMM: O[N,64] = X[N,64] @ W[64,64] ----------------
// 64 rows per block, 256 threads: c = tid&63 (output col), rq = tid>>6 (row quad).
// Xs reads are wave-uniform broadcasts (free); Ws reads are 2-way bank alias (free).
__global__ __launch_bounds__(256) void k_gemm64(const float* __restrict__ X,
                                                const float* __restrict__ W,
                                                float* __restrict__ O, int N) {
    __shared__ float Xs[64][FDIM];
    __shared__ float Ws[64][FDIM];
    const int tid  = threadIdx.x;
    const int base = blockIdx.x * 64;

    // load W (1024 float4)
    #pragma unroll
    for (int i = 0; i < 4; ++i) {
        int idx = tid + i * 256;
        reinterpret_cast<float4*>(&Ws[0][0])[idx] =
            reinterpret_cast<const float4*>(W)[idx];
    }
    // load X tile (1024 float4), guard tail rows
    #pragma unroll
    for (int i = 0; i < 4; ++i) {
        int idx = tid + i * 256;
        int r = idx >> 4;          // 16 float4 per row
        int gr = base + r;
        float4 v = make_float4(0.f, 0.f, 0.f, 0.f);
        if (gr < N) v = reinterpret_cast<const float4*>(X)[(size_t)gr * 16 + (idx & 15)];
        reinterpret_cast<float4*>(&Xs[0][0])[idx] = v;
    }
    __syncthreads();

    const int c  = tid & 63;
    const int rq = tid >> 6;   // 0..3, uniform per wave
    float acc[16];
    #pragma unroll
    for (int j = 0; j < 16; ++j) acc[j] = 0.f;

    #pragma unroll 8
    for (int k = 0; k < 64; ++k) {
        float wv = Ws[k][c];
        #pragma unroll
        for (int j = 0; j < 16; ++j)
            acc[j] = fmaf(Xs[rq * 16 + j][k], wv, acc[j]);
    }

    #pragma unroll
    for (int j = 0; j < 16; ++j) {
        int gr = base + rq * 16 + j;
        if (gr < N) O[(size_t)gr * FDIM + c] = acc[j];
    }
}

// ---------------- edge scatter: agg[dst] += norm * H[src] ----------------
// one edge per 64 lanes; 4 edge-slots per block x 4 iterations = 16 edges/block
__global__ __launch_bounds__(256) void k_scatter(const float* __restrict__ H,
                                                 const int* __restrict__ src,
                                                 const int* __restrict__ dst,
                                                 const float* __restrict__ dinv,
                                                 float* __restrict__ agg, int E, int N) {
    const int lane = threadIdx.x & 63;
    const int esub = threadIdx.x >> 6;     // 0..3
    const int e0 = blockIdx.x * 16 + esub;
    #pragma unroll
    for (int j = 0; j < 4; ++j) {
        int e = e0 + j * 4;
        if (e >= E) continue;
        int s = src[e], d = dst[e];
        if ((unsigned)s >= (unsigned)N || (unsigned)d >= (unsigned)N) continue;
        float nrm = dinv[s] * dinv[d];
        float v = H[(size_t)s * FDIM + lane] * nrm;
        unsafeAtomicAdd(&agg[(size_t)d * FDIM + lane], v);
    }
}

// ---------------- epilogue: agg = [relu](agg + dinv^2 * H + b) in place ----------------
__global__ __launch_bounds__(256) void k_epilogue(float* __restrict__ agg,
                                                  const float* __restrict__ H,
                                                  const float* __restrict__ dinv,
                                                  const float* __restrict__ b,
                                                  int N, int do_relu) {
    int idx = blockIdx.x * 256 + threadIdx.x;   // float4 index
    int total = N * (FDIM / 4);
    if (idx >= total) return;
    int node = idx >> 4;
    int d4   = idx & 15;
    float di = dinv[node];
    float w  = di * di;
    float4 a  = reinterpret_cast<float4*>(agg)[idx];
    float4 h  = reinterpret_cast<const float4*>(H)[idx];
    float4 bb = reinterpret_cast<const float4*>(b)[d4];
    float4 r;
    r.x = fmaf(w, h.x, a.x) + bb.x;
    r.y = fmaf(w, h.y, a.y) + bb.y;
    r.z = fmaf(w, h.z, a.z) + bb.z;
    r.w = fmaf(w, h.w, a.w) + bb.w;
    if (do_relu) {
        r.x = fmaxf(r.x, 0.f); r.y = fmaxf(r.y, 0.f);
        r.z = fmaxf(r.z, 0.f); r.w = fmaxf(r.w, 0.f);
    }
    reinterpret_cast<float4*>(agg)[idx] = r;
}

extern "C" void kernel_launch(void* const* d_in, const int* in_sizes, int n_in,
                              void* d_out, int out_size, void* d_ws, size_t ws_size,
                              hipStream_t stream) {
    const float* x  = (const float*)d_in[0];
    const int*   ei = (const int*)  d_in[1];   // [2, E], int32 (jax demotes int64)
    const float* W1 = (const float*)d_in[2];
    const float* b1 = (const float*)d_in[3];
    const float* W2 = (const float*)d_in[4];
    const float* b2 = (const float*)d_in[5];
    float* out = (float*)d_out;

    const int N = in_sizes[0] / FDIM;   // 100000
    const int E = in_sizes[1] / 2;      // 1600000
    const int* src = ei;
    const int* dst = ei + E;

    // workspace layout: [deg/dinv: N floats][H: N*64][Y: N*64]
    size_t degBytes = ((size_t)N * 4 + 1023) & ~(size_t)1023;
    float* dinv = (float*)d_ws;
    float* H = (float*)((char*)d_ws + degBytes);
    float* Y = H + (size_t)N * FDIM;

    const size_t featBytes = (size_t)N * FDIM * sizeof(float);

    // degree + dinv
    hipMemsetAsync(d_ws, 0, degBytes, stream);
    k_deg<<<2048, 256, 0, stream>>>(dst, (int*)dinv, E, N);
    k_dinv<<<(N + 255) / 256, 256, 0, stream>>>(dinv, N);

    const int gemmBlocks = (N + 63) / 64;
    const int epiBlocks  = (N * (FDIM / 4) + 255) / 256;
    const int scatBlocks = (E + 15) / 16;

    // ---- layer 1 ----
    k_gemm64<<<gemmBlocks, 256, 0, stream>>>(x, W1, H, N);
    hipMemsetAsync(Y, 0, featBytes, stream);
    k_scatter<<<scatBlocks, 256, 0, stream>>>(H, src, dst, dinv, Y, E, N);
    k_epilogue<<<epiBlocks, 256, 0, stream>>>(Y, H, dinv, b1, N, 1);

    // ---- layer 2 ----
    k_gemm64<<<gemmBlocks, 256, 0, stream>>>(Y, W2, H, N);
    hipMemsetAsync(out, 0, featBytes, stream);
    k_scatter<<<scatBlocks, 256, 0, stream>>>(H, src, dst, dinv, out, E, N);
    k_epilogue<<<epiBlocks, 256, 0, stream>>>(out, H, dinv, b2, N, 0);
}

// Round 2
// 423.905 us; speedup vs baseline: 1.9653x; 1.9653x over previous
//
#include <hip/hip_runtime.h>

#define FDIM 64
#define SCHUNK 2048   // scan chunk: 256 threads x 8 elems

// ---------------- degree histogram ----------------
__global__ __launch_bounds__(256) void k_deg(const int* __restrict__ dst,
                                             int* __restrict__ deg, int E, int N) {
    int i = blockIdx.x * 256 + threadIdx.x;
    int stride = gridDim.x * 256;
    for (; i < E; i += stride) {
        int d = dst[i];
        if ((unsigned)d < (unsigned)N) atomicAdd(&deg[d], 1);
    }
}

// dinv[i] = rsqrt(deg[i] + 1)   (+1 = self loop)
__global__ __launch_bounds__(256) void k_dinv(const int* __restrict__ deg,
                                              float* __restrict__ dinv, int N) {
    int i = blockIdx.x * 256 + threadIdx.x;
    if (i < N) dinv[i] = rsqrtf((float)(deg[i] + 1));
}

// ---------------- scan step 1: per-chunk sums ----------------
__global__ __launch_bounds__(256) void k_chunk_sums(const int* __restrict__ deg,
                                                    int* __restrict__ sums, int N) {
    __shared__ int tsum[256];
    int c = blockIdx.x, t = threadIdx.x;
    int base = c * SCHUNK + t * 8;
    int s = 0;
    #pragma unroll
    for (int i = 0; i < 8; ++i) {
        int idx = base + i;
        if (idx < N) s += deg[idx];
    }
    tsum[t] = s;
    __syncthreads();
    for (int off = 128; off > 0; off >>= 1) {
        if (t < off) tsum[t] += tsum[t + off];
        __syncthreads();
    }
    if (t == 0) sums[c] = tsum[0];
}

// ---------------- scan step 2: serial exclusive scan of chunk sums (~49 elems) ----------------
__global__ void k_scan_sums(int* __restrict__ sums, int n) {
    if (blockIdx.x == 0 && threadIdx.x == 0) {
        int run = 0;
        for (int i = 0; i < n; ++i) { int v = sums[i]; sums[i] = run; run += v; }
    }
}

// ---------------- scan step 3: per-chunk exclusive scan -> rowptr, cursor ----------------
__global__ __launch_bounds__(256) void k_scan_chunk(const int* __restrict__ deg,
                                                    const int* __restrict__ chunkBase,
                                                    int* __restrict__ rowptr,
                                                    int* __restrict__ cursor,
                                                    int N, int M /* = N+1 */) {
    __shared__ int tsum[256];
    int c = blockIdx.x, t = threadIdx.x;
    int base = c * SCHUNK + t * 8;
    int v[8];
    int s = 0;
    #pragma unroll
    for (int i = 0; i < 8; ++i) {
        int idx = base + i;
        int d = (idx < N) ? deg[idx] : 0;
        v[i] = s;
        s += d;
    }
    tsum[t] = s;
    __syncthreads();
    for (int off = 1; off < 256; off <<= 1) {
        int x = (t >= off) ? tsum[t - off] : 0;
        __syncthreads();
        tsum[t] += x;
        __syncthreads();
    }
    int tbase = chunkBase[c] + ((t > 0) ? tsum[t - 1] : 0);
    #pragma unroll
    for (int i = 0; i < 8; ++i) {
        int idx = base + i;
        if (idx < M) {
            int val = tbase + v[i];
            rowptr[idx] = val;
            if (idx < N) cursor[idx] = val;
        }
    }
}

// ---------------- CSR fill ----------------
__global__ __launch_bounds__(256) void k_fill(const int* __restrict__ src,
                                              const int* __restrict__ dst,
                                              int* __restrict__ cursor,
                                              int* __restrict__ srcList, int E, int N) {
    int i = blockIdx.x * 256 + threadIdx.x;
    int stride = gridDim.x * 256;
    for (; i < E; i += stride) {
        int d = dst[i], s = src[i];
        if ((unsigned)d < (unsigned)N && (unsigned)s < (unsigned)N) {
            int pos = atomicAdd(&cursor[d], 1);
            srcList[pos] = s;
        }
    }
}

// ---------------- dense GEMM: O[N,64] = X[N,64] @ W[64,64] ----------------
__global__ __launch_bounds__(256) void k_gemm64(const float* __restrict__ X,
                                                const float* __restrict__ W,
                                                float* __restrict__ O, int N) {
    __shared__ float Xs[64][FDIM];
    __shared__ float Ws[64][FDIM];
    const int tid  = threadIdx.x;
    const int base = blockIdx.x * 64;

    #pragma unroll
    for (int i = 0; i < 4; ++i) {
        int idx = tid + i * 256;
        reinterpret_cast<float4*>(&Ws[0][0])[idx] =
            reinterpret_cast<const float4*>(W)[idx];
    }
    #pragma unroll
    for (int i = 0; i < 4; ++i) {
        int idx = tid + i * 256;
        int r = idx >> 4;
        int gr = base + r;
        float4 v = make_float4(0.f, 0.f, 0.f, 0.f);
        if (gr < N) v = reinterpret_cast<const float4*>(X)[(size_t)gr * 16 + (idx & 15)];
        reinterpret_cast<float4*>(&Xs[0][0])[idx] = v;
    }
    __syncthreads();

    const int c  = tid & 63;
    const int rq = tid >> 6;
    float acc[16];
    #pragma unroll
    for (int j = 0; j < 16; ++j) acc[j] = 0.f;

    #pragma unroll 8
    for (int k = 0; k < 64; ++k) {
        float wv = Ws[k][c];
        #pragma unroll
        for (int j = 0; j < 16; ++j)
            acc[j] = fmaf(Xs[rq * 16 + j][k], wv, acc[j]);
    }

    #pragma unroll
    for (int j = 0; j < 16; ++j) {
        int gr = base + rq * 16 + j;
        if (gr < N) O[(size_t)gr * FDIM + c] = acc[j];
    }
}

// ---------------- CSR gather-aggregate + fused epilogue ----------------
// one wave per node; lane = feature.
// out[d] = relu?( di * ( di*H[d] + sum_s dinv[s]*H[s] ) + b )  = di^2 H[d] + sum norm*H[s] + b
__global__ __launch_bounds__(256) void k_agg(const float* __restrict__ H,
                                             const int* __restrict__ rowptr,
                                             const int* __restrict__ srcList,
                                             const float* __restrict__ dinv,
                                             const float* __restrict__ b,
                                             float* __restrict__ O,
                                             int N, int do_relu) {
    const int lane = threadIdx.x & 63;
    const int w    = threadIdx.x >> 6;
    const int node = blockIdx.x * 4 + w;
    if (node >= N) return;

    const int beg = rowptr[node];
    const int end = rowptr[node + 1];
    const float di = dinv[node];

    float acc0 = di * H[(size_t)node * FDIM + lane];   // * di at the end -> di^2 * H[d]
    float acc1 = 0.f;

    for (int k0 = beg; k0 < end; k0 += 64) {
        int kk = k0 + lane;
        int s = 0; float wv = 0.f;
        if (kk < end) { s = srcList[kk]; wv = dinv[s]; }
        int cnt = min(64, end - k0);
        int j = 0;
        for (; j + 1 < cnt; j += 2) {
            int   s0 = __shfl(s,  j,     64);
            int   s1 = __shfl(s,  j + 1, 64);
            float w0 = __shfl(wv, j,     64);
            float w1 = __shfl(wv, j + 1, 64);
            float h0 = H[(size_t)s0 * FDIM + lane];
            float h1 = H[(size_t)s1 * FDIM + lane];
            acc0 = fmaf(w0, h0, acc0);
            acc1 = fmaf(w1, h1, acc1);
        }
        if (j < cnt) {
            int   s0 = __shfl(s,  j, 64);
            float w0 = __shfl(wv, j, 64);
            acc0 = fmaf(w0, H[(size_t)s0 * FDIM + lane], acc0);
        }
    }

    float r = (acc0 + acc1) * di + b[lane];
    if (do_relu) r = fmaxf(r, 0.f);
    O[(size_t)node * FDIM + lane] = r;
}

extern "C" void kernel_launch(void* const* d_in, const int* in_sizes, int n_in,
                              void* d_out, int out_size, void* d_ws, size_t ws_size,
                              hipStream_t stream) {
    const float* x  = (const float*)d_in[0];
    const int*   ei = (const int*)  d_in[1];   // [2, E], int32
    const float* W1 = (const float*)d_in[2];
    const float* b1 = (const float*)d_in[3];
    const float* W2 = (const float*)d_in[4];
    const float* b2 = (const float*)d_in[5];
    float* out = (float*)d_out;

    const int N = in_sizes[0] / FDIM;   // 100000
    const int E = in_sizes[1] / 2;      // 1600000
    const int* src = ei;
    const int* dst = ei + E;

    auto align1k = [](size_t v) { return (v + 1023) & ~(size_t)1023; };
    char* p = (char*)d_ws;
    int*   deg     = (int*)p;                 p += align1k((size_t)N * 4);
    float* dinv    = (float*)p;               p += align1k((size_t)N * 4);
    int*   rowptr  = (int*)p;                 p += align1k((size_t)(N + 1) * 4);
    int*   cursor  = (int*)p;                 p += align1k((size_t)N * 4);
    int*   srcList = (int*)p;                 p += align1k((size_t)E * 4);
    int*   sums    = (int*)p;                 p += align1k((size_t)256 * 4);
    float* H       = (float*)p;               // N*64 floats

    float* Y = out;   // layer-1 activations live in d_out (overwritten by layer 2)

    const int M = N + 1;
    const int numChunks = (M + SCHUNK - 1) / SCHUNK;

    // ---- CSR build ----
    hipMemsetAsync(deg, 0, (size_t)N * 4, stream);
    k_deg<<<2048, 256, 0, stream>>>(dst, deg, E, N);
    k_dinv<<<(N + 255) / 256, 256, 0, stream>>>(deg, dinv, N);
    k_chunk_sums<<<numChunks, 256, 0, stream>>>(deg, sums, N);
    k_scan_sums<<<1, 64, 0, stream>>>(sums, numChunks);
    k_scan_chunk<<<numChunks, 256, 0, stream>>>(deg, sums, rowptr, cursor, N, M);
    k_fill<<<2048, 256, 0, stream>>>(src, dst, cursor, srcList, E, N);

    const int gemmBlocks = (N + 63) / 64;
    const int aggBlocks  = (N + 3) / 4;

    // ---- layer 1 ----
    k_gemm64<<<gemmBlocks, 256, 0, stream>>>(x, W1, H, N);
    k_agg<<<aggBlocks, 256, 0, stream>>>(H, rowptr, srcList, dinv, b1, Y, N, 1);

    // ---- layer 2 ----
    k_gemm64<<<gemmBlocks, 256, 0, stream>>>(Y, W2, H, N);
    k_agg<<<aggBlocks, 256, 0, stream>>>(H, rowptr, srcList, dinv, b2, out, N, 0);
}